// Round 8
// baseline (97.509 us; speedup 1.0000x reference)
//
#include <hip/hip_runtime.h>
#include <stdint.h>

#define NROW 16384
#define DDIM 128
#define ROWB 256            // bytes per row of bf16 z

constexpr int NB     = 64;              // cols per j-tile
constexpr int NJT    = NROW / NB;       // 256 j-tiles across the matrix
constexpr int CHUNK  = 16;              // max j-tiles per block
constexpr int NSTRIP = 128;             // row strips of 128
// strip I has ceil((256-2I)/16) = ceil((128-I)/8) blocks; total = T(128) = 1088
constexpr int NBLK   = 1088;

typedef __bf16 bf16x8 __attribute__((ext_vector_type(8)));
typedef float  f32x4  __attribute__((ext_vector_type(4)));
typedef int    i32x4  __attribute__((ext_vector_type(4)));

typedef const uint32_t __attribute__((address_space(1)))* gptr_t;
typedef uint32_t __attribute__((address_space(3)))*       lptr_t;

__device__ __forceinline__ unsigned short f2bf(float x) {
  union { float f; uint32_t u; } c; c.f = x;
  uint32_t u = c.u + 0x7fffu + ((c.u >> 16) & 1u);   // RNE
  return (unsigned short)(u >> 16);
}

// T(k) = blocks in the LAST k strips = sum_{x=1..k} ceil(x/8)
__device__ __forceinline__ int Tfun(int k) {
  const int q = k >> 3, r = k & 7;
  return 4 * q * (q + 1) + r * (q + 1);
}

// fp32 -> bf16 with the scale folded in: (1/T) * sqrt(log2(e)),
// so the MFMA accumulator equals a*log2(e), ready for v_exp_f32 (exp2).
__global__ __launch_bounds__(256) void prep_kernel(const float* __restrict__ z,
                                                   unsigned short* __restrict__ zs,
                                                   float* __restrict__ s) {
  const float SC = 12.011224087864498f;  // 10 * sqrt(1.4426950408889634)
  int t = blockIdx.x * 256 + threadIdx.x;
  float4 v = reinterpret_cast<const float4*>(z)[t];
  ushort4 o;
  o.x = f2bf(v.x * SC); o.y = f2bf(v.y * SC);
  o.z = f2bf(v.z * SC); o.w = f2bf(v.w * SC);
  reinterpret_cast<ushort4*>(zs)[t] = o;
  if (t < NROW) s[t] = 0.0f;             // rowsum accumulator (ws is poisoned)
}

// Symmetry via 128-row strips: strip I (rows [128I,128I+128)) computes j-tiles
// j >= 2I. Tiles fully right of the diagonal 128-square also contribute
// colsums (= transposed rowsums of the symmetric exp matrix).
//
// Round-8 structure: 3-buffer rotation, ONE s_barrier per tile, staging 2
// tiles ahead (counted vmcnt(4), never drained mid-loop). Safety: at
// barrier_k every wave's iter-(k-1) ds_reads are already in registers (MFMA
// lgkm deps precede barrier arrival), so staging buf[(k+2)%3] -- last read
// at iter k-1 -- after barrier_k is race-free. Own vmcnt(4) before barrier_k
// + barrier => all waves' tile-k loads landed.
// Kept lessons: LDS staging (r5), rolled loop (r3), no forced bounds (r2),
// 32 rows/wave for occupancy (r7).
__global__ __launch_bounds__(256, 2) void gemm_exp_kernel(const unsigned short* __restrict__ zs,
                                                          float* __restrict__ s) {
  __shared__ __align__(16) char smem[3 * NB * ROWB + CHUNK * 64 * 4]; // 48K 3-buf + 4K csm
  float* csm = (float*)(smem + 3 * NB * ROWB);   // shared [CHUNK*64] colsum slab
  const int tid  = threadIdx.x;
  const int lane = tid & 63;
  const int wid  = tid >> 6;

  // blockIdx.x -> (strip I, chunk c): smallest k with T(k) >= NBLK - bid.
  int I, c;
  {
    const int bid = blockIdx.x;
    const int m = NBLK - bid;                   // 1..NBLK
    int k = (int)sqrtf(16.0f * (float)m);       // T(k) ~ k^2/16... inverse guess
    if (k > 128) k = 128;
    if (k < 1) k = 1;
    while (Tfun(k) < m) ++k;
    while (k > 1 && Tfun(k - 1) >= m) --k;
    I = 128 - k;
    c = bid - (NBLK - Tfun(k));
  }
  const int mI     = NJT - 2 * I;                // j-tiles in this strip
  const int jt0    = 2 * I + CHUNK * c;          // first global j-tile
  const int JT_blk = min(CHUNK, mI - CHUNK * c); // tiles this block runs (>=2)

  const int rowBase = I * 128 + wid * 32;        // this wave's 32 rows
  const char* zb = (const char*)zs;
  const int kb = (lane >> 4) << 4;               // 16B chunk within K row

  // Stage j-tile (jt0+k) into buffer `buf`: linear LDS dest + inverse-XOR-
  // swizzled global source; reads apply the same involution (rule #21).
#define STAGE_B(buf, k)                                                          \
  {                                                                              \
    _Pragma("unroll")                                                            \
    for (int i_ = 0; i_ < 4; ++i_) {                                             \
      const int destByte_ = wid * 4096 + i_ * 1024 + lane * 16;                  \
      const int r_  = destByte_ >> 8;                                            \
      const int cb_ = destByte_ & 0xF0;                                          \
      const int srcByte_ = ((jt0 + (k)) * NB + r_) * ROWB                        \
                           + (cb_ ^ ((r_ & 7) << 4));                            \
      __builtin_amdgcn_global_load_lds((gptr_t)(zb + srcByte_),                  \
          (lptr_t)(smem + (buf) * (NB * ROWB) + destByte_), 16, 0, 0);           \
    }                                                                            \
  }

  // Prologue: get tiles 0 and 1 in flight immediately.
  STAGE_B(0, 0);
  if (JT_blk > 1) STAGE_B(1, 1);

  // A fragments: 16x16x32 A layout row=lane&15, k=(lane>>4)*8+e -> 16B/lane
  bf16x8 afrag[2][4];   // [mf][ks]
  {
    const int r0 = rowBase + (lane & 15);
#pragma unroll
    for (int mf = 0; mf < 2; ++mf)
#pragma unroll
      for (int ks = 0; ks < 4; ++ks) {
        i32x4 raw = *reinterpret_cast<const i32x4*>(
            zb + (size_t)(r0 + mf * 16) * ROWB + ks * 64 + kb);
        afrag[mf][ks] = __builtin_bit_cast(bf16x8, raw);
      }
  }

  f32x4 rsv[2];     // rowsum accumulators (vector form -> v_pk_add_f32)
  float cs[4];      // colsum accumulators [nf], ds_add'ed to csm each tile
  rsv[0] = (f32x4){0.f, 0.f, 0.f, 0.f};
  rsv[1] = (f32x4){0.f, 0.f, 0.f, 0.f};
#pragma unroll
  for (int nf = 0; nf < 4; ++nf) cs[nf] = 0.0f;

  // Zero the shared colsum slab; lgkm-drain + barrier so no wave's ds_add
  // races the zeroing. (Plain s_barrier + explicit lgkmcnt keeps the
  // prologue stage loads in flight -- no vmcnt drain here.)
#pragma unroll
  for (int q = 0; q < CHUNK * 64 / 256; ++q) csm[q * 256 + tid] = 0.0f;
  asm volatile("s_waitcnt lgkmcnt(0)" ::: "memory");
  __builtin_amdgcn_s_barrier();

  int cur = 0;      // buffer holding tile k
#pragma unroll 1    // KEEP ROLLED: unrolling pipelines iterations and spills
  for (int k = 0; k < JT_blk; ++k) {
    // Wait own tile-k loads (leave tile-(k+1)'s 4 in flight), sync all waves.
    if (k + 1 < JT_blk) {
      asm volatile("s_waitcnt vmcnt(4)" ::: "memory");
    } else {
      asm volatile("s_waitcnt vmcnt(0)" ::: "memory");
    }
    __builtin_amdgcn_s_barrier();

    // Stage tile k+2 into the buffer last read at iter k-1 (safe post-barrier).
    if (k + 2 < JT_blk) {
      int stg = cur - 1; if (stg < 0) stg += 3;   // (cur+2)%3
      STAGE_B(stg, k + 2);
    }

    f32x4 acc[2][4];
#pragma unroll
    for (int mf = 0; mf < 2; ++mf)
#pragma unroll
      for (int nf = 0; nf < 4; ++nf) {
        f32x4 zv = {0.f, 0.f, 0.f, 0.f};
        acc[mf][nf] = zv;
      }

    const char* bufp = smem + cur * (NB * ROWB);
#pragma unroll
    for (int ks = 0; ks < 4; ++ks) {
      bf16x8 bfrag[4];
#pragma unroll
      for (int nf = 0; nf < 4; ++nf) {
        const int r   = nf * 16 + (lane & 15);
        const int kk  = ks * 64 + kb;
        const int off = r * ROWB + (kk ^ ((r & 7) << 4));
        i32x4 raw = *reinterpret_cast<const i32x4*>(bufp + off);
        bfrag[nf] = __builtin_bit_cast(bf16x8, raw);
      }
#pragma unroll
      for (int mf = 0; mf < 2; ++mf)
#pragma unroll
        for (int nf = 0; nf < 4; ++nf)
          acc[mf][nf] = __builtin_amdgcn_mfma_f32_16x16x32_bf16(
              afrag[mf][ks], bfrag[nf], acc[mf][nf], 0, 0, 0);
    }

    // acc holds a*log2(e) -> exp(a) = exp2(acc); feed row + col accumulators
#pragma unroll
    for (int mf = 0; mf < 2; ++mf)
#pragma unroll
      for (int nf = 0; nf < 4; ++nf) {
        f32x4 a4 = acc[mf][nf];
        f32x4 ev;
        ev[0] = __builtin_amdgcn_exp2f(a4[0]);
        ev[1] = __builtin_amdgcn_exp2f(a4[1]);
        ev[2] = __builtin_amdgcn_exp2f(a4[2]);
        ev[3] = __builtin_amdgcn_exp2f(a4[3]);
        rsv[mf] += ev;
        cs[nf] += (ev[0] + ev[1]) + (ev[2] + ev[3]);
      }

    // Flush colsum partials: reduce the 4 lane-hi groups, one ds_add per col.
#pragma unroll
    for (int nf = 0; nf < 4; ++nf) {
      float v = cs[nf];
      v += __shfl_xor(v, 16);
      v += __shfl_xor(v, 32);
      if (lane < 16) atomicAdd(&csm[k * 64 + nf * 16 + lane], v);
      cs[nf] = 0.0f;
    }

    ++cur; if (cur == 3) cur = 0;
  }
#undef STAGE_B

  // Rowsums: C/D layout col=lane&15, row=(lane>>4)*4+reg. Reduce the 16
  // column-lanes, one atomicAdd per row.
#pragma unroll
  for (int mf = 0; mf < 2; ++mf)
#pragma unroll
    for (int r = 0; r < 4; ++r) {
      float v = rsv[mf][r];
      v += __shfl_xor(v, 1);
      v += __shfl_xor(v, 2);
      v += __shfl_xor(v, 4);
      v += __shfl_xor(v, 8);
      if ((lane & 15) == 0) {
        const int row = rowBase + mf * 16 + ((lane >> 4) << 2) + r;
        atomicAdd(&s[row], v);
      }
    }

  // Colsums: one global atomic per column from the shared slab. Skip columns
  // inside this strip's diagonal 128-square (both (r,c),(c,r) computed there).
  __syncthreads();   // drain csm ds_adds across waves
  {
    const int colBase0 = jt0 * NB;
    const int diagEnd  = (I + 1) * 128;
    const int ncol     = JT_blk * NB;
#pragma unroll
    for (int k4 = 0; k4 < 4; ++k4) {
      const int idx = k4 * 256 + tid;
      if (idx < ncol) {
        const int col = colBase0 + idx;
        if (col >= diagEnd) atomicAdd(&s[col], csm[idx]);
      }
    }
  }
}

__global__ __launch_bounds__(1024) void reduce_kernel(const float* __restrict__ s,
                                                      float* __restrict__ out) {
  const int tid = threadIdx.x;
  float acc = 0.0f;
  for (int i = tid; i < NROW; i += 1024) acc += __log2f(s[i]);
#pragma unroll
  for (int m = 32; m >= 1; m >>= 1) acc += __shfl_xor(acc, m);
  __shared__ float wsum[16];
  if ((tid & 63) == 0) wsum[tid >> 6] = acc;
  __syncthreads();
  if (tid == 0) {
    float tot = 0.0f;
#pragma unroll
    for (int w = 0; w < 16; ++w) tot += wsum[w];
    // mean(-log(sum/N)) = log N - (ln2/N) * sum(log2 s_i)
    out[0] = logf((float)NROW) - 0.6931471805599453f * tot / (float)NROW;
  }
}

extern "C" void kernel_launch(void* const* d_in, const int* in_sizes, int n_in,
                              void* d_out, int out_size, void* d_ws, size_t ws_size,
                              hipStream_t stream) {
  const float* z = (const float*)d_in[0];
  unsigned short* zs = (unsigned short*)d_ws;                       // 4 MB bf16
  float* s = (float*)((char*)d_ws + (size_t)NROW * DDIM * 2);       // 64 KB rowsums
  float* out = (float*)d_out;

  prep_kernel<<<dim3(NROW * DDIM / 4 / 256), dim3(256), 0, stream>>>(z, zs, s);
  gemm_exp_kernel<<<dim3(NBLK), dim3(256), 0, stream>>>(zs, s);
  reduce_kernel<<<dim3(1), dim3(1024), 0, stream>>>(s, out);
}

// Round 9
// 86.204 us; speedup vs baseline: 1.1311x; 1.1311x over previous
//
#include <hip/hip_runtime.h>
#include <stdint.h>

#define NROW 16384
#define DDIM 128
#define ROWB 256            // bytes per row of bf16 z

constexpr int NB     = 64;              // cols per j-tile
constexpr int NJT    = NROW / NB;       // 256 j-tiles across the matrix
constexpr int CHUNK  = 8;               // max j-tiles per block
constexpr int NSTRIP = 128;             // row strips of 128
// strip I has ceil((256-2I)/8) = ceil((128-I)/4) blocks; total = S(128) = 2112
constexpr int NBLK   = 2112;

typedef __bf16 bf16x8 __attribute__((ext_vector_type(8)));
typedef float  f32x4  __attribute__((ext_vector_type(4)));
typedef int    i32x4  __attribute__((ext_vector_type(4)));

typedef const uint32_t __attribute__((address_space(1)))* gptr_t;
typedef uint32_t __attribute__((address_space(3)))*       lptr_t;

__device__ __forceinline__ unsigned short f2bf(float x) {
  union { float f; uint32_t u; } c; c.f = x;
  uint32_t u = c.u + 0x7fffu + ((c.u >> 16) & 1u);   // RNE
  return (unsigned short)(u >> 16);
}

// S(k) = sum_{x=1..k} ceil(x/4)  (blocks in the last k strips)
__device__ __forceinline__ int Sfun(int k) {
  const int q = k >> 2, r = k & 3;
  return 2 * q * (q + 1) + r * (q + 1);
}

// fp32 -> bf16 with the scale folded in: (1/T) * sqrt(log2(e)),
// so the MFMA accumulator equals a*log2(e), ready for v_exp_f32 (exp2).
__global__ __launch_bounds__(256) void prep_kernel(const float* __restrict__ z,
                                                   unsigned short* __restrict__ zs,
                                                   float* __restrict__ s) {
  const float SC = 12.011224087864498f;  // 10 * sqrt(1.4426950408889634)
  int t = blockIdx.x * 256 + threadIdx.x;
  float4 v = reinterpret_cast<const float4*>(z)[t];
  ushort4 o;
  o.x = f2bf(v.x * SC); o.y = f2bf(v.y * SC);
  o.z = f2bf(v.z * SC); o.w = f2bf(v.w * SC);
  reinterpret_cast<ushort4*>(zs)[t] = o;
  if (t < NROW) s[t] = 0.0f;             // rowsum accumulator (ws is poisoned)
}

// Symmetry via 128-row strips: strip I (rows [128I,128I+128)) computes j-tiles
// j >= 2I. Tiles fully right of the diagonal 128-square also contribute
// colsums (= transposed rowsums of the symmetric exp matrix).
//
// Round-9 structure: MAX OCCUPANCY. Rounds 1-8 showed per-tile pipe
// efficiency is invariant (~14 us MFMA-busy floor); wall time = floor /
// fill-fraction, and fill tracks resident blocks/CU (r7: 2->4 blocks won;
// r8: 4->3 lost). So: single 16 KB staging buffer + 2 KB shared colsum slab
// = 18 KB LDS -> 8 blocks/CU; VGPR ~60 -> 8 waves/SIMD. The naive
// stage->drain->barrier->compute->barrier schedule exposes ~600cy of staging
// latency per block, filled by the other 7 blocks' compute (TLP, not ILP).
// Kept: rolled loop (r3), no forced bounds (r2), 32 rows/wave (r7).
__global__ __launch_bounds__(256, 2) void gemm_exp_kernel(const unsigned short* __restrict__ zs,
                                                          float* __restrict__ s) {
  __shared__ __align__(16) char smem[NB * ROWB + CHUNK * 64 * 4]; // 16K buf + 2K csm
  float* csm = (float*)(smem + NB * ROWB);       // shared [CHUNK*64] colsum slab
  const int tid  = threadIdx.x;
  const int lane = tid & 63;
  const int wid  = tid >> 6;

  // blockIdx.x -> (strip I, chunk c): smallest k with S(k) >= NBLK - bid.
  int I, c;
  {
    const int bid = blockIdx.x;
    const int m = NBLK - bid;
    int k = (int)sqrtf(8.0f * (float)m);
    if (k > 128) k = 128;
    if (k < 1) k = 1;
    while (Sfun(k) < m) ++k;
    while (k > 1 && Sfun(k - 1) >= m) --k;
    I = 128 - k;
    c = bid - (NBLK - Sfun(k));
  }
  const int mI     = NJT - 2 * I;                // j-tiles in this strip
  const int jt0    = 2 * I + CHUNK * c;          // first global j-tile
  const int JT_blk = min(CHUNK, mI - CHUNK * c); // tiles this block runs

  const int rowBase = I * 128 + wid * 32;        // this wave's 32 rows
  const char* zb = (const char*)zs;
  const int kb = (lane >> 4) << 4;               // 16B chunk within K row

  // A fragments: 16x16x32 A layout row=lane&15, k=(lane>>4)*8+e -> 16B/lane
  bf16x8 afrag[2][4];   // [mf][ks]
  {
    const int r0 = rowBase + (lane & 15);
#pragma unroll
    for (int mf = 0; mf < 2; ++mf)
#pragma unroll
      for (int ks = 0; ks < 4; ++ks) {
        i32x4 raw = *reinterpret_cast<const i32x4*>(
            zb + (size_t)(r0 + mf * 16) * ROWB + ks * 64 + kb);
        afrag[mf][ks] = __builtin_bit_cast(bf16x8, raw);
      }
  }

  f32x4 rsv[2];     // rowsum accumulators
  float cs[4];      // colsum accumulators [nf], ds_add'ed to csm each tile
  rsv[0] = (f32x4){0.f, 0.f, 0.f, 0.f};
  rsv[1] = (f32x4){0.f, 0.f, 0.f, 0.f};
#pragma unroll
  for (int nf = 0; nf < 4; ++nf) cs[nf] = 0.0f;

  // Zero the shared colsum slab. Own writes drain via lgkmcnt; iter-0's
  // barrier publishes them to all waves before any flush atomic.
  csm[tid] = 0.0f;
  csm[256 + tid] = 0.0f;
  asm volatile("s_waitcnt lgkmcnt(0)" ::: "memory");

  // Stage j-tile (jt0+k): linear LDS dest + inverse-XOR-swizzled global
  // source; reads apply the same involution (rule #21).
#define STAGE_B(k)                                                               \
  {                                                                              \
    _Pragma("unroll")                                                            \
    for (int i_ = 0; i_ < 4; ++i_) {                                             \
      const int destByte_ = wid * 4096 + i_ * 1024 + lane * 16;                  \
      const int r_  = destByte_ >> 8;                                            \
      const int cb_ = destByte_ & 0xF0;                                          \
      const int srcByte_ = ((jt0 + (k)) * NB + r_) * ROWB                        \
                           + (cb_ ^ ((r_ & 7) << 4));                            \
      __builtin_amdgcn_global_load_lds((gptr_t)(zb + srcByte_),                  \
          (lptr_t)(smem + destByte_), 16, 0, 0);                                 \
    }                                                                            \
  }

#pragma unroll 1    // KEEP ROLLED: unrolling pipelines iterations and spills
  for (int k = 0; k < JT_blk; ++k) {
    // Stage tile k (overwrite-safe: end-barrier of iter k-1 guarantees all
    // waves finished reading the buffer), drain, publish.
    STAGE_B(k);
    asm volatile("s_waitcnt vmcnt(0)" ::: "memory");
    __builtin_amdgcn_s_barrier();

    f32x4 acc[2][4];
#pragma unroll
    for (int mf = 0; mf < 2; ++mf)
#pragma unroll
      for (int nf = 0; nf < 4; ++nf) {
        f32x4 zv = {0.f, 0.f, 0.f, 0.f};
        acc[mf][nf] = zv;
      }

#pragma unroll
    for (int ks = 0; ks < 4; ++ks) {
      bf16x8 bfrag[4];
#pragma unroll
      for (int nf = 0; nf < 4; ++nf) {
        const int r   = nf * 16 + (lane & 15);
        const int kk  = ks * 64 + kb;
        const int off = r * ROWB + (kk ^ ((r & 7) << 4));
        i32x4 raw = *reinterpret_cast<const i32x4*>(smem + off);
        bfrag[nf] = __builtin_bit_cast(bf16x8, raw);
      }
#pragma unroll
      for (int mf = 0; mf < 2; ++mf)
#pragma unroll
        for (int nf = 0; nf < 4; ++nf)
          acc[mf][nf] = __builtin_amdgcn_mfma_f32_16x16x32_bf16(
              afrag[mf][ks], bfrag[nf], acc[mf][nf], 0, 0, 0);
    }

    // acc holds a*log2(e) -> exp(a) = exp2(acc); feed row + col accumulators
#pragma unroll
    for (int mf = 0; mf < 2; ++mf)
#pragma unroll
      for (int nf = 0; nf < 4; ++nf) {
        f32x4 a4 = acc[mf][nf];
        f32x4 ev;
        ev[0] = __builtin_amdgcn_exp2f(a4[0]);
        ev[1] = __builtin_amdgcn_exp2f(a4[1]);
        ev[2] = __builtin_amdgcn_exp2f(a4[2]);
        ev[3] = __builtin_amdgcn_exp2f(a4[3]);
        rsv[mf] += ev;
        cs[nf] += (ev[0] + ev[1]) + (ev[2] + ev[3]);
      }

    // Flush colsum partials: reduce the 4 lane-hi groups, one ds_add per col
    // into the shared slab (atomic across the 4 waves).
#pragma unroll
    for (int nf = 0; nf < 4; ++nf) {
      float v = cs[nf];
      v += __shfl_xor(v, 16);
      v += __shfl_xor(v, 32);
      if (lane < 16) atomicAdd(&csm[k * 64 + nf * 16 + lane], v);
      cs[nf] = 0.0f;
    }

    __builtin_amdgcn_s_barrier();   // all waves done reading buf
  }
#undef STAGE_B

  // Rowsums: C/D layout col=lane&15, row=(lane>>4)*4+reg. Reduce the 16
  // column-lanes, one atomicAdd per row.
#pragma unroll
  for (int mf = 0; mf < 2; ++mf)
#pragma unroll
    for (int r = 0; r < 4; ++r) {
      float v = rsv[mf][r];
      v += __shfl_xor(v, 1);
      v += __shfl_xor(v, 2);
      v += __shfl_xor(v, 4);
      v += __shfl_xor(v, 8);
      if ((lane & 15) == 0) {
        const int row = rowBase + mf * 16 + ((lane >> 4) << 2) + r;
        atomicAdd(&s[row], v);
      }
    }

  // Colsums: one global atomic per column from the shared slab. Skip columns
  // inside this strip's diagonal 128-square (both (r,c),(c,r) computed there).
  __syncthreads();   // drain csm ds_adds across waves
  {
    const int colBase0 = jt0 * NB;
    const int diagEnd  = (I + 1) * 128;
    const int ncol     = JT_blk * NB;
#pragma unroll
    for (int k4 = 0; k4 < 2; ++k4) {
      const int idx = k4 * 256 + tid;
      if (idx < ncol) {
        const int col = colBase0 + idx;
        if (col >= diagEnd) atomicAdd(&s[col], csm[idx]);
      }
    }
  }
}

__global__ __launch_bounds__(1024) void reduce_kernel(const float* __restrict__ s,
                                                      float* __restrict__ out) {
  const int tid = threadIdx.x;
  float acc = 0.0f;
  for (int i = tid; i < NROW; i += 1024) acc += __log2f(s[i]);
#pragma unroll
  for (int m = 32; m >= 1; m >>= 1) acc += __shfl_xor(acc, m);
  __shared__ float wsum[16];
  if ((tid & 63) == 0) wsum[tid >> 6] = acc;
  __syncthreads();
  if (tid == 0) {
    float tot = 0.0f;
#pragma unroll
    for (int w = 0; w < 16; ++w) tot += wsum[w];
    // mean(-log(sum/N)) = log N - (ln2/N) * sum(log2 s_i)
    out[0] = logf((float)NROW) - 0.6931471805599453f * tot / (float)NROW;
  }
}

extern "C" void kernel_launch(void* const* d_in, const int* in_sizes, int n_in,
                              void* d_out, int out_size, void* d_ws, size_t ws_size,
                              hipStream_t stream) {
  const float* z = (const float*)d_in[0];
  unsigned short* zs = (unsigned short*)d_ws;                       // 4 MB bf16
  float* s = (float*)((char*)d_ws + (size_t)NROW * DDIM * 2);       // 64 KB rowsums
  float* out = (float*)d_out;

  prep_kernel<<<dim3(NROW * DDIM / 4 / 256), dim3(256), 0, stream>>>(z, zs, s);
  gemm_exp_kernel<<<dim3(NBLK), dim3(256), 0, stream>>>(zs, s);
  reduce_kernel<<<dim3(1), dim3(1024), 0, stream>>>(s, out);
}

// Round 10
// 65.336 us; speedup vs baseline: 1.4924x; 1.3194x over previous
//
#include <hip/hip_runtime.h>
#include <stdint.h>

#define NROW 16384
#define DDIM 128
#define ROWB 256            // bytes per row of bf16 z

constexpr int NB     = 64;              // cols per j-tile
constexpr int NJT    = NROW / NB;       // 256 j-tiles across the matrix
constexpr int CHUNK  = 8;               // max j-tiles per block
constexpr int NSTRIP = 128;             // row strips of 128
// strip I has ceil((256-2I)/8) = ceil((128-I)/4) blocks; total = S(128) = 2112
constexpr int NBLK   = 2112;

typedef __bf16 bf16x8 __attribute__((ext_vector_type(8)));
typedef float  f32x4  __attribute__((ext_vector_type(4)));
typedef int    i32x4  __attribute__((ext_vector_type(4)));

typedef const uint32_t __attribute__((address_space(1)))* gptr_t;
typedef uint32_t __attribute__((address_space(3)))*       lptr_t;

__device__ __forceinline__ unsigned short f2bf(float x) {
  union { float f; uint32_t u; } c; c.f = x;
  uint32_t u = c.u + 0x7fffu + ((c.u >> 16) & 1u);   // RNE
  return (unsigned short)(u >> 16);
}

// S(k) = sum_{x=1..k} ceil(x/4)  (blocks in the last k strips)
__device__ __forceinline__ int Sfun(int k) {
  const int q = k >> 2, r = k & 3;
  return 2 * q * (q + 1) + r * (q + 1);
}

// fp32 -> bf16 with the scale folded in: (1/T) * sqrt(log2(e)),
// so the MFMA accumulator equals a*log2(e), ready for v_exp_f32 (exp2).
__global__ __launch_bounds__(256) void prep_kernel(const float* __restrict__ z,
                                                   unsigned short* __restrict__ zs,
                                                   float* __restrict__ s) {
  const float SC = 12.011224087864498f;  // 10 * sqrt(1.4426950408889634)
  int t = blockIdx.x * 256 + threadIdx.x;
  float4 v = reinterpret_cast<const float4*>(z)[t];
  ushort4 o;
  o.x = f2bf(v.x * SC); o.y = f2bf(v.y * SC);
  o.z = f2bf(v.z * SC); o.w = f2bf(v.w * SC);
  reinterpret_cast<ushort4*>(zs)[t] = o;
  if (t < NROW) s[t] = 0.0f;             // rowsum accumulator (ws is poisoned)
}

// Symmetry via 128-row strips: strip I (rows [128I,128I+128)) computes j-tiles
// j >= 2I. Tiles fully right of the diagonal 128-square also contribute
// colsums (= transposed rowsums of the symmetric exp matrix).
//
// Round-10 = round-7 (best: 60.1us) + two surgical changes:
//  (a) FULL-NIBBLE LDS swizzle (r&15)<<4 instead of (r&7)<<4: rows are 256B
//      = 16 slots; the old 3-bit swizzle left lanes 0-15 and 16-31 on the
//      same 8 slots (slot set closed under XOR of the kb=16 bit) -> measured
//      4.2M conflict cycles (~4cy extra per ds_read_b128). Nibble swizzle
//      spreads 16 rows over 16 slots (2 lanes/bank = free). Applied
//      both-sides: inverse on global source, same involution on reads.
//  (b) s_setprio(1) around the ds_read+MFMA phase (T5): each SIMD hosts
//      waves of ~4 DIFFERENT blocks at independent phases -> scheduler can
//      prefer compute-phase waves over stage/flush-phase waves.
// Kept: depth-1 counted-vmcnt 2-buffer staging (r7/r9 A/B: worth ~18us),
// rolled loop (r3), no forced bounds (r2), 32 rows/wave (r7).
__global__ __launch_bounds__(256, 2) void gemm_exp_kernel(const unsigned short* __restrict__ zs,
                                                          float* __restrict__ s) {
  __shared__ __align__(16) char smem[2 * NB * ROWB + 4 * CHUNK * 64 * 4]; // 32K dbuf + 8K csm
  float* csm = (float*)(smem + 2 * NB * ROWB);   // [4 waves][CHUNK*64 cols]
  const int tid  = threadIdx.x;
  const int lane = tid & 63;
  const int wid  = tid >> 6;

  // blockIdx.x -> (strip I, chunk c): smallest k with S(k) >= NBLK - bid.
  int I, c;
  {
    const int bid = blockIdx.x;
    const int m = NBLK - bid;
    int k = (int)sqrtf(8.0f * (float)m);
    if (k > 128) k = 128;
    if (k < 1) k = 1;
    while (Sfun(k) < m) ++k;
    while (k > 1 && Sfun(k - 1) >= m) --k;
    I = 128 - k;
    c = bid - (NBLK - Sfun(k));
  }
  const int mI     = NJT - 2 * I;                // j-tiles in this strip
  const int jt0    = 2 * I + CHUNK * c;          // first global j-tile
  const int JT_blk = min(CHUNK, mI - CHUNK * c); // tiles this block runs

  const int rowBase = I * 128 + wid * 32;        // this wave's 32 rows
  const char* zb = (const char*)zs;
  const int kb = (lane >> 4) << 4;               // 16B chunk within K row

  // A fragments: 16x16x32 A layout row=lane&15, k=(lane>>4)*8+e -> 16B/lane
  bf16x8 afrag[2][4];   // [mf][ks]
  {
    const int r0 = rowBase + (lane & 15);
#pragma unroll
    for (int mf = 0; mf < 2; ++mf)
#pragma unroll
      for (int ks = 0; ks < 4; ++ks) {
        i32x4 raw = *reinterpret_cast<const i32x4*>(
            zb + (size_t)(r0 + mf * 16) * ROWB + ks * 64 + kb);
        afrag[mf][ks] = __builtin_bit_cast(bf16x8, raw);
      }
  }

  f32x4 rsv[2];     // rowsum accumulators
  float cs[4];      // colsum accumulators [nf], flushed to LDS each j-tile
  rsv[0] = (f32x4){0.f, 0.f, 0.f, 0.f};
  rsv[1] = (f32x4){0.f, 0.f, 0.f, 0.f};
#pragma unroll
  for (int nf = 0; nf < 4; ++nf) cs[nf] = 0.0f;

  // Stage j-tile (jt0+k): linear LDS dest + inverse-nibble-swizzled global
  // source; reads apply the same involution (rule #21).
#define STAGE_B(buf, k)                                                          \
  {                                                                              \
    _Pragma("unroll")                                                            \
    for (int i_ = 0; i_ < 4; ++i_) {                                             \
      const int destByte_ = wid * 4096 + i_ * 1024 + lane * 16;                  \
      const int r_  = destByte_ >> 8;                                            \
      const int cb_ = destByte_ & 0xF0;                                          \
      const int srcByte_ = ((jt0 + (k)) * NB + r_) * ROWB                        \
                           + (cb_ ^ ((r_ & 15) << 4));                           \
      __builtin_amdgcn_global_load_lds((gptr_t)(zb + srcByte_),                  \
          (lptr_t)(smem + (buf) * (NB * ROWB) + destByte_), 16, 0, 0);           \
    }                                                                            \
  }

  STAGE_B(0, 0);

#pragma unroll 1   // KEEP ROLLED: unrolling pipelines iterations and spills
  for (int k = 0; k < JT_blk; ++k) {
    const int cur = k & 1;
    if (k + 1 < JT_blk) {
      STAGE_B(cur ^ 1, k + 1);
      asm volatile("s_waitcnt vmcnt(4)" ::: "memory");  // current tile landed
    } else {
      asm volatile("s_waitcnt vmcnt(0)" ::: "memory");
    }
    __builtin_amdgcn_s_barrier();

    f32x4 acc[2][4];
#pragma unroll
    for (int mf = 0; mf < 2; ++mf)
#pragma unroll
      for (int nf = 0; nf < 4; ++nf) {
        f32x4 zv = {0.f, 0.f, 0.f, 0.f};
        acc[mf][nf] = zv;
      }

    // Compute phase at raised priority: waves of other blocks on this SIMD
    // that are in their stage/flush phase yield issue slots to us.
    __builtin_amdgcn_s_setprio(1);
    const char* bufp = smem + cur * (NB * ROWB);
#pragma unroll
    for (int ks = 0; ks < 4; ++ks) {
      bf16x8 bfrag[4];
#pragma unroll
      for (int nf = 0; nf < 4; ++nf) {
        const int r   = nf * 16 + (lane & 15);
        const int kk  = ks * 64 + kb;
        const int off = r * ROWB + (kk ^ ((r & 15) << 4));
        i32x4 raw = *reinterpret_cast<const i32x4*>(bufp + off);
        bfrag[nf] = __builtin_bit_cast(bf16x8, raw);
      }
#pragma unroll
      for (int mf = 0; mf < 2; ++mf)
#pragma unroll
        for (int nf = 0; nf < 4; ++nf)
          acc[mf][nf] = __builtin_amdgcn_mfma_f32_16x16x32_bf16(
              afrag[mf][ks], bfrag[nf], acc[mf][nf], 0, 0, 0);
    }
    __builtin_amdgcn_s_setprio(0);

    // acc holds a*log2(e) -> exp(a) = exp2(acc); feed row + col accumulators
#pragma unroll
    for (int mf = 0; mf < 2; ++mf)
#pragma unroll
      for (int nf = 0; nf < 4; ++nf) {
        f32x4 a4 = acc[mf][nf];
        f32x4 ev;
        ev[0] = __builtin_amdgcn_exp2f(a4[0]);
        ev[1] = __builtin_amdgcn_exp2f(a4[1]);
        ev[2] = __builtin_amdgcn_exp2f(a4[2]);
        ev[3] = __builtin_amdgcn_exp2f(a4[3]);
        rsv[mf] += ev;
        cs[nf] += (ev[0] + ev[1]) + (ev[2] + ev[3]);
      }

    // Flush colsum partials for this tile into the per-wave LDS slab.
#pragma unroll
    for (int nf = 0; nf < 4; ++nf) {
      float v = cs[nf];
      v += __shfl_xor(v, 16);
      v += __shfl_xor(v, 32);
      if (lane < 16) csm[wid * (CHUNK * 64) + k * 64 + nf * 16 + lane] = v;
      cs[nf] = 0.0f;
    }

    __builtin_amdgcn_s_barrier();   // all waves done reading buf[cur]
  }
#undef STAGE_B

  // Rowsums: C/D layout col=lane&15, row=(lane>>4)*4+reg. Reduce the 16
  // column-lanes, one atomicAdd per row.
#pragma unroll
  for (int mf = 0; mf < 2; ++mf)
#pragma unroll
    for (int r = 0; r < 4; ++r) {
      float v = rsv[mf][r];
      v += __shfl_xor(v, 1);
      v += __shfl_xor(v, 2);
      v += __shfl_xor(v, 4);
      v += __shfl_xor(v, 8);
      if ((lane & 15) == 0) {
        const int row = rowBase + mf * 16 + ((lane >> 4) << 2) + r;
        atomicAdd(&s[row], v);
      }
    }

  // Colsums: combine the 4 per-wave slabs, one atomic per column. Skip
  // columns inside this strip's diagonal 128-square (computed fully there).
  __syncthreads();   // drain csm ds_writes across waves
  {
    const int colBase0 = jt0 * NB;
    const int diagEnd  = (I + 1) * 128;
    const int ncol     = JT_blk * NB;
#pragma unroll
    for (int k4 = 0; k4 < 2; ++k4) {
      const int idx = k4 * 256 + tid;
      if (idx < ncol) {
        const int col = colBase0 + idx;
        if (col >= diagEnd) {
          float sum = csm[idx] + csm[CHUNK * 64 + idx]
                    + csm[2 * CHUNK * 64 + idx] + csm[3 * CHUNK * 64 + idx];
          atomicAdd(&s[col], sum);
        }
      }
    }
  }
}

__global__ __launch_bounds__(1024) void reduce_kernel(const float* __restrict__ s,
                                                      float* __restrict__ out) {
  const int tid = threadIdx.x;
  float acc = 0.0f;
  for (int i = tid; i < NROW; i += 1024) acc += __log2f(s[i]);
#pragma unroll
  for (int m = 32; m >= 1; m >>= 1) acc += __shfl_xor(acc, m);
  __shared__ float wsum[16];
  if ((tid & 63) == 0) wsum[tid >> 6] = acc;
  __syncthreads();
  if (tid == 0) {
    float tot = 0.0f;
#pragma unroll
    for (int w = 0; w < 16; ++w) tot += wsum[w];
    // mean(-log(sum/N)) = log N - (ln2/N) * sum(log2 s_i)
    out[0] = logf((float)NROW) - 0.6931471805599453f * tot / (float)NROW;
  }
}

extern "C" void kernel_launch(void* const* d_in, const int* in_sizes, int n_in,
                              void* d_out, int out_size, void* d_ws, size_t ws_size,
                              hipStream_t stream) {
  const float* z = (const float*)d_in[0];
  unsigned short* zs = (unsigned short*)d_ws;                       // 4 MB bf16
  float* s = (float*)((char*)d_ws + (size_t)NROW * DDIM * 2);       // 64 KB rowsums
  float* out = (float*)d_out;

  prep_kernel<<<dim3(NROW * DDIM / 4 / 256), dim3(256), 0, stream>>>(z, zs, s);
  gemm_exp_kernel<<<dim3(NBLK), dim3(256), 0, stream>>>(zs, s);
  reduce_kernel<<<dim3(1), dim3(1024), 0, stream>>>(s, out);
}